// Round 2
// baseline (799.543 us; speedup 1.0000x reference)
//
#include <hip/hip_runtime.h>
#include <stdint.h>

#pragma clang fp contract(off)

typedef unsigned long long ull;

#define HIGHT 0.7f
#define LOWT  0.3f
#define KSEL  128
#define NBIN  16384       // top-14-bit key histogram
#define CAP   2048        // candidate buffer per mode (expected ~140 pos / ~700 neg)
#define MAXGT 512
#define COLCH 8           // col-kernel proposal chunks

// ---- monotonic key: descending float value, ties -> ascending index ----
__device__ __forceinline__ unsigned key32_of_float(float f){
  unsigned u = __float_as_uint(f);
  return (u & 0x80000000u) ? ~u : (u | 0x80000000u);
}
__device__ __forceinline__ ull pack_key(unsigned k32, unsigned idx){
  return ((ull)k32 << 32) | (ull)(0xFFFFFFFFu - idx);
}
__device__ __forceinline__ unsigned idx_of_key(ull k){
  return 0xFFFFFFFFu - (unsigned)(k & 0xFFFFFFFFull);
}

// ---- bit-exact IoU (matches numpy fp32 op-for-op; no contraction) ----
__device__ __forceinline__ float iou_pair(float ax0, float ay0, float ax1, float ay1, float aarea,
                                          float bx0, float by0, float bx1, float by1, float barea){
#pragma clang fp contract(off)
  float x0 = fmaxf(ax0, bx0);
  float y0 = fmaxf(ay0, by0);
  float x1 = fminf(ax1, bx1);
  float y1 = fminf(ay1, by1);
  float dx = fmaxf(x1 - x0, 0.0f);
  float dy = fmaxf(y1 - y0, 0.0f);
  float inter = dx * dy;
  float uni = (aarea + barea) - inter;
  return inter / uni;                 // exact IEEE fp32 div
}

__device__ __forceinline__ ull shfl_xor_u64(ull v, int m){
  int lo = __shfl_xor((int)(unsigned)(v & 0xFFFFFFFFull), m, 64);
  int hi = __shfl_xor((int)(unsigned)(v >> 32), m, 64);
  return ((ull)(unsigned)hi << 32) | (unsigned)lo;
}

// ---- K0: zero hist / forced / colbest / counters ----
__global__ void init_kernel(int* __restrict__ hist, int histn,
                            unsigned* __restrict__ forcedw, int fw,
                            ull* __restrict__ colbest, int n2,
                            int* __restrict__ neg_count, int* __restrict__ cnt){
  int t = blockIdx.x * blockDim.x + threadIdx.x;
  if (t < histn) hist[t] = 0;
  if (t < fw) forcedw[t] = 0u;
  if (t < n2) colbest[t] = 0ull;
  if (t == 0){ *neg_count = 0; cnt[0] = 0; cnt[1] = 0; }
}

// ---- K1: per-proposal max+argmax over GTs; 4 threads per proposal ----
__global__ void row_kernel(const float4* __restrict__ boxes, const float4* __restrict__ gts,
                           int n1, int n2,
                           float* __restrict__ max_iou, int* __restrict__ input_idx){
#pragma clang fp contract(off)
  __shared__ float4 gc[MAXGT];
  __shared__ float  ga[MAXGT];
  for (int j = threadIdx.x; j < n2; j += blockDim.x){
    float4 g = gts[j];
    float hw = g.z * 0.5f, hh = g.w * 0.5f;
    gc[j] = make_float4(g.x - hw, g.y - hh, g.x + hw, g.y + hh);
    ga[j] = g.z * g.w;
  }
  __syncthreads();
  int t = blockIdx.x * blockDim.x + threadIdx.x;
  int i = t >> 2;
  int p = t & 3;
  if (i >= n1) return;
  float4 pb = boxes[i];
  float hw = pb.z * 0.5f, hh = pb.w * 0.5f;
  float px0 = pb.x - hw, py0 = pb.y - hh, px1 = pb.x + hw, py1 = pb.y + hh;
  float pa = pb.z * pb.w;
  int q = (n2 + 3) >> 2;
  int jlo = p * q, jhi = min(jlo + q, n2);
  ull best = 0;
#pragma unroll 4
  for (int j = jlo; j < jhi; ++j){
    float4 g = gc[j];
    float v = iou_pair(px0, py0, px1, py1, pa, g.x, g.y, g.z, g.w, ga[j]);
    ull key = pack_key(key32_of_float(v), (unsigned)j);
    if (key > best) best = key;
  }
  ull o = shfl_xor_u64(best, 1); if (o > best) best = o;
  o = shfl_xor_u64(best, 2);     if (o > best) best = o;
  if (p == 0){
    unsigned k32 = (unsigned)(best >> 32);
    float v = (k32 & 0x80000000u) ? __uint_as_float(k32 & 0x7FFFFFFFu)
                                  : __uint_as_float(~k32);
    max_iou[i] = v;
    input_idx[i] = (int)idx_of_key(best);
  }
}

// ---- K2: per-GT argmax over proposals; grid (n2, COLCH), atomicMax merge ----
__global__ void col_kernel(const float4* __restrict__ boxes, const float4* __restrict__ gts,
                           int n1, ull* __restrict__ colbest){
#pragma clang fp contract(off)
  int j = blockIdx.x;
  int c = blockIdx.y;
  int cs = (n1 + COLCH - 1) / COLCH;
  int lo = c * cs, hi = min(lo + cs, n1);
  float4 g = gts[j];
  float ghw = g.z * 0.5f, ghh = g.w * 0.5f;
  float gx0 = g.x - ghw, gy0 = g.y - ghh, gx1 = g.x + ghw, gy1 = g.y + ghh;
  float garea = g.z * g.w;
  ull best = 0;
  for (int i = lo + threadIdx.x; i < hi; i += blockDim.x){
    float4 p = boxes[i];
    float phw = p.z * 0.5f, phh = p.w * 0.5f;
    float v = iou_pair(p.x - phw, p.y - phh, p.x + phw, p.y + phh, p.z * p.w,
                       gx0, gy0, gx1, gy1, garea);
    ull key = pack_key(key32_of_float(v), (unsigned)i);
    if (key > best) best = key;
  }
  __shared__ ull red[256];
  red[threadIdx.x] = best;
  __syncthreads();
  for (int s = 128; s > 0; s >>= 1){
    if (threadIdx.x < s && red[threadIdx.x + s] > red[threadIdx.x])
      red[threadIdx.x] = red[threadIdx.x + s];
    __syncthreads();
  }
  if (threadIdx.x == 0) atomicMax(&colbest[j], red[0]);
}

// ---- K3: forced-positive scatter ----
__global__ void scatter_kernel(const ull* __restrict__ colbest, int n2,
                               unsigned char* __restrict__ forced){
  int j = blockIdx.x * blockDim.x + threadIdx.x;
  if (j < n2) forced[idx_of_key(colbest[j])] = 1;
}

// ---- K4: histograms (pos / normal-neg / fallback-neg) + neg count ----
__global__ void hist_kernel(const float* __restrict__ max_iou, const unsigned char* __restrict__ forced,
                            const float* __restrict__ pn, const float* __restrict__ nn,
                            int n1, int* __restrict__ hist, int* __restrict__ neg_count){
  int i = blockIdx.x * blockDim.x + threadIdx.x;
  if (i >= n1) return;
  float m = max_iou[i];
  bool f = forced[i] != 0;
  bool pos = (m > HIGHT) || f;
  float ni = nn[i];
  float s0 = pos ? pn[i] : -1.0f;
  atomicAdd(&hist[key32_of_float(s0) >> 18], 1);
  bool nm = (m < LOWT) && !f;
  float s1 = nm ? ni : -1.0f;
  atomicAdd(&hist[NBIN + (key32_of_float(s1) >> 18)], 1);
  float s2 = (!pos) ? ni : -1.0f;
  atomicAdd(&hist[2 * NBIN + (key32_of_float(s2) >> 18)], 1);
  if (nm) atomicAdd(neg_count, 1);
}

// ---- K5: find threshold bin b* (suffix count >= KSEL); 3 blocks ----
__global__ void thresh_kernel(const int* __restrict__ hist, int* __restrict__ bstar){
  const int* h = hist + blockIdx.x * NBIN;
  __shared__ int suf[256];
  __shared__ int s_b, s_cum;
  int tid = threadIdx.x;
  if (tid == 0){ s_b = -1; s_cum = 0; }
  __syncthreads();
  // scores < 2.0 always -> key32 < 0xC0000000 -> bin <= 0x2FE0 -> chunk <= 47
  for (int c = 47; c >= 0; --c){
    suf[tid] = h[c * 256 + tid];
    __syncthreads();
    for (int off = 1; off < 256; off <<= 1){
      int x = (tid + off < 256) ? suf[tid + off] : 0;
      __syncthreads();
      suf[tid] += x;
      __syncthreads();
    }
    int cum = s_cum;
    int mine = cum + suf[tid];
    int nxt = (tid < 255) ? (cum + suf[tid + 1]) : cum;
    if (mine >= KSEL && nxt < KSEL) s_b = c * 256 + tid;
    __syncthreads();
    if (s_b >= 0) break;
    if (tid == 0) s_cum = cum + suf[0];
    __syncthreads();
  }
  if (tid == 0) bstar[blockIdx.x] = (s_b >= 0) ? s_b : 0;
}

// ---- K6: collect candidates with bin >= b* ----
__global__ void collect_kernel(const float* __restrict__ max_iou, const unsigned char* __restrict__ forced,
                               const float* __restrict__ pn, const float* __restrict__ nn,
                               int n1, const int* __restrict__ bstar, const int* __restrict__ neg_count,
                               int* __restrict__ cnt, ull* __restrict__ cand){
  int i = blockIdx.x * blockDim.x + threadIdx.x;
  if (i >= n1) return;
  float m = max_iou[i];
  bool f = forced[i] != 0;
  bool pos = (m > HIGHT) || f;
  float s0 = pos ? pn[i] : -1.0f;
  unsigned k0 = key32_of_float(s0);
  if ((int)(k0 >> 18) >= bstar[0]){
    int p = atomicAdd(&cnt[0], 1);
    if (p < CAP) cand[p] = pack_key(k0, (unsigned)i);
  }
  bool fb = (*neg_count == 0);
  bool nm = fb ? (!pos) : ((m < LOWT) && !f);
  float s1 = nm ? nn[i] : -1.0f;
  unsigned k1 = key32_of_float(s1);
  if ((int)(k1 >> 18) >= bstar[fb ? 2 : 1]){
    int p = atomicAdd(&cnt[1], 1);
    if (p < CAP) cand[CAP + p] = pack_key(k1, (unsigned)i);
  }
}

// ---- K7: exact rank-select of top-128 (keys unique); 2 blocks x 1024 thr ----
__global__ void final_kernel(const ull* __restrict__ cand, const int* __restrict__ cnt,
                             const int* __restrict__ input_idx, int* __restrict__ out){
  int mode = blockIdx.x;
  __shared__ ull keys[CAP];
  int n = min(cnt[mode], CAP);
  for (int t = threadIdx.x; t < n; t += blockDim.x)
    keys[t] = cand[mode * CAP + t];
  __syncthreads();
  ull mykey[2]; int myrank[2]; int ne = 0;
  for (int t = threadIdx.x; t < n; t += blockDim.x){
    mykey[ne] = keys[t]; myrank[ne] = 0; ne++;
  }
  for (int o = 0; o < n; ++o){
    ull ko = keys[o];
    if (ne > 0) myrank[0] += (ko > mykey[0]);
    if (ne > 1) myrank[1] += (ko > mykey[1]);
  }
  for (int e = 0; e < ne; ++e){
    int r = myrank[e];
    if (r < KSEL){
      unsigned idx = idx_of_key(mykey[e]);
      if (mode == 0){
        out[r] = (int)idx;
        out[KSEL + r] = input_idx[idx];
      } else {
        out[2 * KSEL + r] = (int)idx;
      }
    }
  }
}

extern "C" void kernel_launch(void* const* d_in, const int* in_sizes, int n_in,
                              void* d_out, int out_size, void* d_ws, size_t ws_size,
                              hipStream_t stream){
  const float4* boxes = (const float4*)d_in[0];
  const float4* gts   = (const float4*)d_in[1];
  const float* pos_noise = (const float*)d_in[2];
  const float* neg_noise = (const float*)d_in[3];
  const int n1 = in_sizes[0] / 4;
  const int n2 = in_sizes[1] / 4;
  int* out = (int*)d_out;

  char* ws = (char*)d_ws;
  size_t off = 0;
  auto carve = [&](size_t bytes) -> char* {
    char* p = ws + off;
    off = (off + bytes + 255) & ~(size_t)255;
    return p;
  };
  int*   hist      = (int*)  carve((size_t)3 * NBIN * 4);
  float* max_iou   = (float*)carve((size_t)n1 * 4);
  int*   input_idx = (int*)  carve((size_t)n1 * 4);
  unsigned char* forced = (unsigned char*)carve(((size_t)n1 + 3) & ~(size_t)3);
  ull*   colbest   = (ull*)  carve((size_t)n2 * 8);
  int*   neg_count = (int*)  carve(4);
  int*   cnt       = (int*)  carve(8);
  int*   bstar     = (int*)  carve(12);
  ull*   cand      = (ull*)  carve((size_t)2 * CAP * 8);

  const int histn = 3 * NBIN;
  const int fw = (n1 + 3) / 4;
  int initn = histn; if (fw > initn) initn = fw; if (n2 > initn) initn = n2;

  init_kernel<<<(initn + 255) / 256, 256, 0, stream>>>(hist, histn, (unsigned*)forced, fw,
                                                       colbest, n2, neg_count, cnt);
  row_kernel<<<(n1 * 4 + 255) / 256, 256, 0, stream>>>(boxes, gts, n1, n2, max_iou, input_idx);
  dim3 gcol(n2, COLCH);
  col_kernel<<<gcol, 256, 0, stream>>>(boxes, gts, n1, colbest);
  scatter_kernel<<<(n2 + 255) / 256, 256, 0, stream>>>(colbest, n2, forced);
  hist_kernel<<<(n1 + 255) / 256, 256, 0, stream>>>(max_iou, forced, pos_noise, neg_noise,
                                                    n1, hist, neg_count);
  thresh_kernel<<<3, 256, 0, stream>>>(hist, bstar);
  collect_kernel<<<(n1 + 255) / 256, 256, 0, stream>>>(max_iou, forced, pos_noise, neg_noise,
                                                       n1, bstar, neg_count, cnt, cand);
  final_kernel<<<2, 1024, 0, stream>>>(cand, cnt, input_idx, out);
}

// Round 3
// 177.805 us; speedup vs baseline: 4.4967x; 4.4967x over previous
//
#include <hip/hip_runtime.h>
#include <stdint.h>

#pragma clang fp contract(off)

typedef unsigned long long ull;

#define HIGHT 0.7f
#define LOWT  0.3f
#define KSEL  128
#define NBIN  16384       // top-14-bit key histogram
#define CAP   2048        // candidate buffer per mode
#define MAXGT 512
#define COLCH 8           // col-kernel proposal chunks
#define NEG1K 0x407FFFFFu // key32_of_float(-1.0f)

// ---- monotonic key: descending float value, ties -> ascending index ----
__device__ __forceinline__ unsigned key32_of_float(float f){
  unsigned u = __float_as_uint(f);
  return (u & 0x80000000u) ? ~u : (u | 0x80000000u);
}
__device__ __forceinline__ ull pack_key(unsigned k32, unsigned idx){
  return ((ull)k32 << 32) | (ull)(0xFFFFFFFFu - idx);
}
__device__ __forceinline__ unsigned idx_of_key(ull k){
  return 0xFFFFFFFFu - (unsigned)(k & 0xFFFFFFFFull);
}

// ---- bit-exact IoU (matches numpy fp32 op-for-op; no contraction) ----
__device__ __forceinline__ float iou_pair(float ax0, float ay0, float ax1, float ay1, float aarea,
                                          float bx0, float by0, float bx1, float by1, float barea){
#pragma clang fp contract(off)
  float x0 = fmaxf(ax0, bx0);
  float y0 = fmaxf(ay0, by0);
  float x1 = fminf(ax1, bx1);
  float y1 = fminf(ay1, by1);
  float dx = fmaxf(x1 - x0, 0.0f);
  float dy = fmaxf(y1 - y0, 0.0f);
  float inter = dx * dy;
  float uni = (aarea + barea) - inter;
  return inter / uni;                 // exact IEEE fp32 div
}

__device__ __forceinline__ ull shfl_xor_u64(ull v, int m){
  int lo = __shfl_xor((int)(unsigned)(v & 0xFFFFFFFFull), m, 64);
  int hi = __shfl_xor((int)(unsigned)(v >> 32), m, 64);
  return ((ull)(unsigned)hi << 32) | (unsigned)lo;
}

// ---- K0: zero hist / forced / colbest / counters ----
__global__ void init_kernel(int* __restrict__ hist, int histn,
                            unsigned* __restrict__ forcedw, int fw,
                            ull* __restrict__ colbest, int n2,
                            int* __restrict__ neg_count, int* __restrict__ cnt){
  int t = blockIdx.x * blockDim.x + threadIdx.x;
  if (t < histn) hist[t] = 0;
  if (t < fw) forcedw[t] = 0u;
  if (t < n2) colbest[t] = 0ull;
  if (t == 0){ *neg_count = 0; cnt[0] = 0; cnt[1] = 0; }
}

// ---- K1: per-proposal max+argmax over GTs; 4 threads per proposal ----
__global__ void row_kernel(const float4* __restrict__ boxes, const float4* __restrict__ gts,
                           int n1, int n2,
                           float* __restrict__ max_iou, int* __restrict__ input_idx){
#pragma clang fp contract(off)
  __shared__ float4 gc[MAXGT];
  __shared__ float  ga[MAXGT];
  for (int j = threadIdx.x; j < n2; j += blockDim.x){
    float4 g = gts[j];
    float hw = g.z * 0.5f, hh = g.w * 0.5f;
    gc[j] = make_float4(g.x - hw, g.y - hh, g.x + hw, g.y + hh);
    ga[j] = g.z * g.w;
  }
  __syncthreads();
  int t = blockIdx.x * blockDim.x + threadIdx.x;
  int i = t >> 2;
  int p = t & 3;
  if (i >= n1) return;
  float4 pb = boxes[i];
  float hw = pb.z * 0.5f, hh = pb.w * 0.5f;
  float px0 = pb.x - hw, py0 = pb.y - hh, px1 = pb.x + hw, py1 = pb.y + hh;
  float pa = pb.z * pb.w;
  int q = (n2 + 3) >> 2;
  int jlo = p * q, jhi = min(jlo + q, n2);
  ull best = 0;
#pragma unroll 4
  for (int j = jlo; j < jhi; ++j){
    float4 g = gc[j];
    float v = iou_pair(px0, py0, px1, py1, pa, g.x, g.y, g.z, g.w, ga[j]);
    ull key = pack_key(key32_of_float(v), (unsigned)j);
    if (key > best) best = key;
  }
  ull o = shfl_xor_u64(best, 1); if (o > best) best = o;
  o = shfl_xor_u64(best, 2);     if (o > best) best = o;
  if (p == 0){
    unsigned k32 = (unsigned)(best >> 32);
    float v = (k32 & 0x80000000u) ? __uint_as_float(k32 & 0x7FFFFFFFu)
                                  : __uint_as_float(~k32);
    max_iou[i] = v;
    input_idx[i] = (int)idx_of_key(best);
  }
}

// ---- K2: per-GT argmax over proposals; grid (n2, COLCH), atomicMax merge ----
__global__ void col_kernel(const float4* __restrict__ boxes, const float4* __restrict__ gts,
                           int n1, ull* __restrict__ colbest){
#pragma clang fp contract(off)
  int j = blockIdx.x;
  int c = blockIdx.y;
  int cs = (n1 + COLCH - 1) / COLCH;
  int lo = c * cs, hi = min(lo + cs, n1);
  float4 g = gts[j];
  float ghw = g.z * 0.5f, ghh = g.w * 0.5f;
  float gx0 = g.x - ghw, gy0 = g.y - ghh, gx1 = g.x + ghw, gy1 = g.y + ghh;
  float garea = g.z * g.w;
  ull best = 0;
  for (int i = lo + threadIdx.x; i < hi; i += blockDim.x){
    float4 p = boxes[i];
    float phw = p.z * 0.5f, phh = p.w * 0.5f;
    float v = iou_pair(p.x - phw, p.y - phh, p.x + phw, p.y + phh, p.z * p.w,
                       gx0, gy0, gx1, gy1, garea);
    ull key = pack_key(key32_of_float(v), (unsigned)i);
    if (key > best) best = key;
  }
  __shared__ ull red[256];
  red[threadIdx.x] = best;
  __syncthreads();
  for (int s = 128; s > 0; s >>= 1){
    if (threadIdx.x < s && red[threadIdx.x + s] > red[threadIdx.x])
      red[threadIdx.x] = red[threadIdx.x + s];
    __syncthreads();
  }
  if (threadIdx.x == 0) atomicMax(&colbest[j], red[0]);
}

// ---- K3: forced-positive scatter ----
__global__ void scatter_kernel(const ull* __restrict__ colbest, int n2,
                               unsigned char* __restrict__ forced){
  int j = blockIdx.x * blockDim.x + threadIdx.x;
  if (j < n2) forced[idx_of_key(colbest[j])] = 1;
}

// ---- K4: histograms of REAL scores only (pos / normal-neg / fallback-neg) ----
// (-1.0 sentinel scores are NOT histogrammed: they all share one bin and
//  serialize the atomic pipe — the R2 634us regression)
__global__ void hist_kernel(const float* __restrict__ max_iou, const unsigned char* __restrict__ forced,
                            const float* __restrict__ pn, const float* __restrict__ nn,
                            int n1, int* __restrict__ hist, int* __restrict__ neg_count){
  int i = blockIdx.x * blockDim.x + threadIdx.x;
  if (i >= n1) return;
  float m = max_iou[i];
  bool f = forced[i] != 0;
  bool pos = (m > HIGHT) || f;
  float ni = nn[i];
  if (pos) atomicAdd(&hist[key32_of_float(pn[i]) >> 18], 1);
  bool nm = (m < LOWT) && !f;
  if (nm) atomicAdd(&hist[NBIN + (key32_of_float(ni) >> 18)], 1);
  if (!pos) atomicAdd(&hist[2 * NBIN + (key32_of_float(ni) >> 18)], 1);
  if (nm) atomicAdd(neg_count, 1);   // uniform addr: wave-coalesced by compiler
}

// ---- K5: threshold bin b* (suffix count >= KSEL) + total real count; 3 blocks ----
__global__ void thresh_kernel(const int* __restrict__ hist, int* __restrict__ bstar){
  const int* h = hist + blockIdx.x * NBIN;
  __shared__ int suf[256];
  __shared__ int s_b, s_cum;
  int tid = threadIdx.x;
  if (tid == 0){ s_b = -1; s_cum = 0; }
  __syncthreads();
  // real scores in [0,1): key32 in [0x80000000, 0xBF800000) -> chunks 32..47
  for (int c = 47; c >= 31; --c){
    suf[tid] = h[c * 256 + tid];
    __syncthreads();
    for (int off = 1; off < 256; off <<= 1){
      int x = (tid + off < 256) ? suf[tid + off] : 0;
      __syncthreads();
      suf[tid] += x;
      __syncthreads();
    }
    int cum = s_cum;
    int mine = cum + suf[tid];
    int nxt = (tid < 255) ? (cum + suf[tid + 1]) : cum;
    if (mine >= KSEL && nxt < KSEL) s_b = c * 256 + tid;
    __syncthreads();
    if (s_b >= 0) break;
    if (tid == 0) s_cum = cum + suf[0];
    __syncthreads();
  }
  if (tid == 0){
    bstar[blockIdx.x] = (s_b >= 0) ? s_b : 0;
    bstar[3 + blockIdx.x] = (s_b >= 0) ? KSEL : s_cum;  // tot (exact only when < KSEL)
  }
}

// ---- K6: collect candidates with bin >= b*; deterministic -1 fill if tot<KSEL ----
__global__ void collect_kernel(const float* __restrict__ max_iou, const unsigned char* __restrict__ forced,
                               const float* __restrict__ pn, const float* __restrict__ nn,
                               int n1, const int* __restrict__ bstar, const int* __restrict__ neg_count,
                               int* __restrict__ cnt, ull* __restrict__ cand){
  int i = blockIdx.x * blockDim.x + threadIdx.x;
  if (i >= n1) return;
  float m = max_iou[i];
  bool f = forced[i] != 0;
  bool pos = (m > HIGHT) || f;
  if (pos){
    unsigned k0 = key32_of_float(pn[i]);
    if ((int)(k0 >> 18) >= bstar[0]){
      int p = atomicAdd(&cnt[0], 1);
      if (p < CAP) cand[p] = pack_key(k0, (unsigned)i);
    }
  } else if (bstar[3] < KSEL && i < 2 * KSEL){
    // fewer than KSEL real positives: ref top_k picks -1-scored entries by
    // ascending index; the (KSEL-tot)-th lowest masked-out index is < 2*KSEL
    int p = atomicAdd(&cnt[0], 1);
    if (p < CAP) cand[p] = pack_key(NEG1K, (unsigned)i);
  }
  bool fb = (*neg_count == 0);
  bool nm = fb ? (!pos) : ((m < LOWT) && !f);
  int hsel = fb ? 2 : 1;
  if (nm){
    unsigned k1 = key32_of_float(nn[i]);
    if ((int)(k1 >> 18) >= bstar[hsel]){
      int p = atomicAdd(&cnt[1], 1);
      if (p < CAP) cand[CAP + p] = pack_key(k1, (unsigned)i);
    }
  } else if (bstar[3 + hsel] < KSEL && i < 2 * KSEL){
    int p = atomicAdd(&cnt[1], 1);
    if (p < CAP) cand[CAP + p] = pack_key(NEG1K, (unsigned)i);
  }
}

// ---- K7: exact rank-select of top-128 (keys totally ordered, unique); 2 blocks ----
__global__ void final_kernel(const ull* __restrict__ cand, const int* __restrict__ cnt,
                             const int* __restrict__ input_idx, int* __restrict__ out){
  int mode = blockIdx.x;
  __shared__ ull keys[CAP];
  int n = min(cnt[mode], CAP);
  for (int t = threadIdx.x; t < n; t += blockDim.x)
    keys[t] = cand[mode * CAP + t];
  __syncthreads();
  ull mykey[2]; int myrank[2]; int ne = 0;
  for (int t = threadIdx.x; t < n; t += blockDim.x){
    mykey[ne] = keys[t]; myrank[ne] = 0; ne++;
  }
  for (int o = 0; o < n; ++o){
    ull ko = keys[o];
    if (ne > 0) myrank[0] += (ko > mykey[0]);
    if (ne > 1) myrank[1] += (ko > mykey[1]);
  }
  for (int e = 0; e < ne; ++e){
    int r = myrank[e];
    if (r < KSEL){
      unsigned idx = idx_of_key(mykey[e]);
      if (mode == 0){
        out[r] = (int)idx;
        out[KSEL + r] = input_idx[idx];
      } else {
        out[2 * KSEL + r] = (int)idx;
      }
    }
  }
}

extern "C" void kernel_launch(void* const* d_in, const int* in_sizes, int n_in,
                              void* d_out, int out_size, void* d_ws, size_t ws_size,
                              hipStream_t stream){
  const float4* boxes = (const float4*)d_in[0];
  const float4* gts   = (const float4*)d_in[1];
  const float* pos_noise = (const float*)d_in[2];
  const float* neg_noise = (const float*)d_in[3];
  const int n1 = in_sizes[0] / 4;
  const int n2 = in_sizes[1] / 4;
  int* out = (int*)d_out;

  char* ws = (char*)d_ws;
  size_t off = 0;
  auto carve = [&](size_t bytes) -> char* {
    char* p = ws + off;
    off = (off + bytes + 255) & ~(size_t)255;
    return p;
  };
  int*   hist      = (int*)  carve((size_t)3 * NBIN * 4);
  float* max_iou   = (float*)carve((size_t)n1 * 4);
  int*   input_idx = (int*)  carve((size_t)n1 * 4);
  unsigned char* forced = (unsigned char*)carve(((size_t)n1 + 3) & ~(size_t)3);
  ull*   colbest   = (ull*)  carve((size_t)n2 * 8);
  int*   neg_count = (int*)  carve(4);
  int*   cnt       = (int*)  carve(8);
  int*   bstar     = (int*)  carve(24);
  ull*   cand      = (ull*)  carve((size_t)2 * CAP * 8);

  const int histn = 3 * NBIN;
  const int fw = (n1 + 3) / 4;
  int initn = histn; if (fw > initn) initn = fw; if (n2 > initn) initn = n2;

  init_kernel<<<(initn + 255) / 256, 256, 0, stream>>>(hist, histn, (unsigned*)forced, fw,
                                                       colbest, n2, neg_count, cnt);
  row_kernel<<<(n1 * 4 + 255) / 256, 256, 0, stream>>>(boxes, gts, n1, n2, max_iou, input_idx);
  dim3 gcol(n2, COLCH);
  col_kernel<<<gcol, 256, 0, stream>>>(boxes, gts, n1, colbest);
  scatter_kernel<<<(n2 + 255) / 256, 256, 0, stream>>>(colbest, n2, forced);
  hist_kernel<<<(n1 + 255) / 256, 256, 0, stream>>>(max_iou, forced, pos_noise, neg_noise,
                                                    n1, hist, neg_count);
  thresh_kernel<<<3, 256, 0, stream>>>(hist, bstar);
  collect_kernel<<<(n1 + 255) / 256, 256, 0, stream>>>(max_iou, forced, pos_noise, neg_noise,
                                                       n1, bstar, neg_count, cnt, cand);
  final_kernel<<<2, 1024, 0, stream>>>(cand, cnt, input_idx, out);
}